// Round 1
// baseline (290.339 us; speedup 1.0000x reference)
//
#include <hip/hip_runtime.h>
#include <hip/hip_bf16.h>

typedef __bf16 bf16_t;
typedef __bf16 bf16x8 __attribute__((ext_vector_type(8)));
typedef float f32x4 __attribute__((ext_vector_type(4)));

constexpr int Bz = 8, Lseq = 1024, Dm = 512, Hh = 8, DKd = 64;
constexpr int MTOK = Bz * Lseq;   // 8192 tokens
constexpr int NREL = 201;

// ---------------- fp32 -> bf16 cast ----------------
__global__ __launch_bounds__(256) void k_cast(const float* __restrict__ s,
                                              bf16_t* __restrict__ d, int n) {
  int i = (blockIdx.x * 256 + threadIdx.x) * 4;
  if (i < n) {
    float4 v = *reinterpret_cast<const float4*>(s + i);
    d[i + 0] = (bf16_t)v.x;
    d[i + 1] = (bf16_t)v.y;
    d[i + 2] = (bf16_t)v.z;
    d[i + 3] = (bf16_t)v.w;
  }
}

// ---------------- y = A @ W^T  (A:[8192][512] bf16, W:[512][512] bf16) --------
// MODE 0: store bf16 head-major   out[(b*8+h)*1024+q][64]   (Qh / Kh)
// MODE 1: store bf16 head-transposed out[(b*8+h)*64+d][1024] (Vt)
// MODE 2: store fp32 row-major + residual add (pre-LN x)
template <int MODE>
__global__ __launch_bounds__(256) void k_gemm512(const bf16_t* __restrict__ A,
                                                 const bf16_t* __restrict__ W,
                                                 bf16_t* __restrict__ outb,
                                                 float* __restrict__ outf,
                                                 const float* __restrict__ resid) {
  const int lane = threadIdx.x & 63, w = threadIdx.x >> 6;
  const int lr = lane & 15, lg = lane >> 4;
  const int Rbase = blockIdx.y * 64 + (w >> 1) * 32;
  const int Cbase = blockIdx.x * 64 + (w & 1) * 32;

  f32x4 acc[2][2] = {};
  for (int k0 = 0; k0 < Dm; k0 += 32) {
    bf16x8 af[2], wf[2];
#pragma unroll
    for (int i = 0; i < 2; ++i)
      af[i] = *reinterpret_cast<const bf16x8*>(A + (size_t)(Rbase + i * 16 + lr) * Dm + k0 + lg * 8);
#pragma unroll
    for (int j = 0; j < 2; ++j)
      wf[j] = *reinterpret_cast<const bf16x8*>(W + (size_t)(Cbase + j * 16 + lr) * Dm + k0 + lg * 8);
#pragma unroll
    for (int i = 0; i < 2; ++i)
#pragma unroll
      for (int j = 0; j < 2; ++j)
        acc[i][j] = __builtin_amdgcn_mfma_f32_16x16x32_bf16(af[i], wf[j], acc[i][j], 0, 0, 0);
  }
#pragma unroll
  for (int i = 0; i < 2; ++i)
#pragma unroll
    for (int j = 0; j < 2; ++j)
#pragma unroll
      for (int r = 0; r < 4; ++r) {
        const int gr = Rbase + i * 16 + lg * 4 + r;  // token row
        const int gc = Cbase + j * 16 + lr;          // output col
        const float vv = acc[i][j][r];
        if (MODE == 0) {
          const int bb = gr >> 10, qq = gr & 1023, hh = gc >> 6, dd = gc & 63;
          outb[(((size_t)(bb * Hh + hh)) * Lseq + qq) * DKd + dd] = (bf16_t)vv;
        } else if (MODE == 1) {
          const int bb = gr >> 10, qq = gr & 1023, hh = gc >> 6, dd = gc & 63;
          outb[(((size_t)(bb * Hh + hh)) * DKd + dd) * Lseq + qq] = (bf16_t)vv;
        } else {
          const size_t idx = (size_t)gr * Dm + gc;
          outf[idx] = vv + resid[idx];
        }
      }
}

// ---------------- pos_dot[bh*L+q][r] = Qh[bh*L+q][:] . rel[r][:] --------------
__global__ __launch_bounds__(256) void k_posdot(const bf16_t* __restrict__ Qh,
                                                const bf16_t* __restrict__ relb,
                                                bf16_t* __restrict__ posd) {
  const int lane = threadIdx.x & 63, w = threadIdx.x >> 6;
  const int lr = lane & 15, lg = lane >> 4;
  const int m0 = blockIdx.y * 64 + w * 16;
  const int n0 = blockIdx.x * 16;
  const int r = n0 + lr;

  bf16x8 a0 = *reinterpret_cast<const bf16x8*>(Qh + (size_t)(m0 + lr) * DKd + lg * 8);
  bf16x8 a1 = *reinterpret_cast<const bf16x8*>(Qh + (size_t)(m0 + lr) * DKd + 32 + lg * 8);
  bf16x8 b0 = {}, b1 = {};
  if (r < NREL) {
    b0 = *reinterpret_cast<const bf16x8*>(relb + (size_t)r * DKd + lg * 8);
    b1 = *reinterpret_cast<const bf16x8*>(relb + (size_t)r * DKd + 32 + lg * 8);
  }
  f32x4 acc = {};
  acc = __builtin_amdgcn_mfma_f32_16x16x32_bf16(a0, b0, acc, 0, 0, 0);
  acc = __builtin_amdgcn_mfma_f32_16x16x32_bf16(a1, b1, acc, 0, 0, 0);
#pragma unroll
  for (int rr = 0; rr < 4; ++rr) {
    const int row = m0 + lg * 4 + rr;
    const int col = n0 + lr;
    if (col < NREL) posd[(size_t)row * NREL + col] = (bf16_t)acc[rr];
  }
}

// ---------------- flash attention, 1 wave per (bh, 16 q-rows) -----------------
__global__ __launch_bounds__(64) void k_attn(const bf16_t* __restrict__ Qh,
                                             const bf16_t* __restrict__ Kh,
                                             const bf16_t* __restrict__ Vt,
                                             const bf16_t* __restrict__ posd,
                                             bf16_t* __restrict__ attnb) {
  __shared__ bf16_t pos_lds[16 * NREL];
  __shared__ bf16_t Pbuf[16][32];

  const int bid = blockIdx.x;
  const int bh = bid >> 6;           // 0..63
  const int qbase = (bid & 63) << 4; // 16-row q tile
  const int lane = threadIdx.x;
  const int lr = lane & 15, lg = lane >> 4;

  const bf16_t* Qp = Qh + ((size_t)bh * Lseq + qbase) * DKd;
  const bf16_t* Kp = Kh + (size_t)bh * Lseq * DKd;
  const bf16_t* Vp = Vt + (size_t)bh * DKd * Lseq;
  const bf16_t* pp = posd + ((size_t)bh * Lseq + qbase) * NREL;

  for (int i = lane; i < 16 * NREL; i += 64) pos_lds[i] = pp[i];
  __syncthreads();

  const bf16x8 aq0 = *reinterpret_cast<const bf16x8*>(Qp + lr * DKd + lg * 8);
  const bf16x8 aq1 = *reinterpret_cast<const bf16x8*>(Qp + lr * DKd + 32 + lg * 8);

  f32x4 Oacc[4] = {};
  float mrow[4] = {-1e30f, -1e30f, -1e30f, -1e30f};
  float lsum[4] = {0.f, 0.f, 0.f, 0.f};

  for (int k0 = 0; k0 < Lseq; k0 += 32) {
    f32x4 st[2];
#pragma unroll
    for (int t = 0; t < 2; ++t) {
      const bf16_t* kp = Kp + (size_t)(k0 + t * 16 + lr) * DKd + lg * 8;
      bf16x8 bk0 = *reinterpret_cast<const bf16x8*>(kp);
      bf16x8 bk1 = *reinterpret_cast<const bf16x8*>(kp + 32);
      f32x4 a = {};
      a = __builtin_amdgcn_mfma_f32_16x16x32_bf16(aq0, bk0, a, 0, 0, 0);
      a = __builtin_amdgcn_mfma_f32_16x16x32_bf16(aq1, bk1, a, 0, 0, 0);
      st[t] = a;
    }
    // add relative-position term, scale by 1/sqrt(dk)
    float sv[2][4], pvv[2][4];
#pragma unroll
    for (int t = 0; t < 2; ++t)
#pragma unroll
      for (int r = 0; r < 4; ++r) {
        const int ql = lg * 4 + r;            // local q row
        const int kg = k0 + t * 16 + lr;      // global k col
        int rel = qbase + ql - kg;
        rel = rel < -100 ? -100 : (rel > 100 ? 100 : rel);
        sv[t][r] = (st[t][r] + (float)pos_lds[ql * NREL + rel + 100]) * 0.125f;
      }
    // online softmax (rows live in 16-lane groups)
#pragma unroll
    for (int r = 0; r < 4; ++r) {
      float tm = fmaxf(sv[0][r], sv[1][r]);
#pragma unroll
      for (int mk = 1; mk < 16; mk <<= 1) tm = fmaxf(tm, __shfl_xor(tm, mk, 16));
      const float mn = fmaxf(mrow[r], tm);
      const float sc = __expf(mrow[r] - mn);
      const float p0 = __expf(sv[0][r] - mn);
      const float p1 = __expf(sv[1][r] - mn);
      pvv[0][r] = p0; pvv[1][r] = p1;
      float ps = p0 + p1;
#pragma unroll
      for (int mk = 1; mk < 16; mk <<= 1) ps += __shfl_xor(ps, mk, 16);
      lsum[r] = lsum[r] * sc + ps;
      mrow[r] = mn;
#pragma unroll
      for (int f = 0; f < 4; ++f) Oacc[f][r] *= sc;
    }
    // route P through LDS: D-layout -> A-layout transpose
    __syncthreads();   // prior iteration's Pbuf reads complete
#pragma unroll
    for (int t = 0; t < 2; ++t)
#pragma unroll
      for (int r = 0; r < 4; ++r)
        Pbuf[lg * 4 + r][t * 16 + lr] = (bf16_t)pvv[t][r];
    __syncthreads();
    const bf16x8 ap = *reinterpret_cast<const bf16x8*>(&Pbuf[lr][lg * 8]);
#pragma unroll
    for (int f = 0; f < 4; ++f) {
      bf16x8 bv = *reinterpret_cast<const bf16x8*>(Vp + (size_t)(f * 16 + lr) * Lseq + k0 + lg * 8);
      Oacc[f] = __builtin_amdgcn_mfma_f32_16x16x32_bf16(ap, bv, Oacc[f], 0, 0, 0);
    }
  }

  const int gb = bh >> 3, hh = bh & 7;
#pragma unroll
  for (int r = 0; r < 4; ++r) {
    const float inv = 1.0f / lsum[r];
    const int qg = qbase + lg * 4 + r;
    bf16_t* op = attnb + ((size_t)(gb * Lseq + qg)) * Dm + hh * DKd;
#pragma unroll
    for (int f = 0; f < 4; ++f) op[f * 16 + lr] = (bf16_t)(Oacc[f][r] * inv);
  }
}

// ---------------- row LayerNorm over D=512 ------------------------------------
__global__ __launch_bounds__(256) void k_ln(const float* __restrict__ y,
                                            const float* __restrict__ g,
                                            const float* __restrict__ be,
                                            float* __restrict__ out) {
  const int row = blockIdx.x * 4 + (threadIdx.x >> 6);
  const int lane = threadIdx.x & 63;
  const float* yp = y + (size_t)row * Dm + lane * 8;
  float4 v0 = *reinterpret_cast<const float4*>(yp);
  float4 v1 = *reinterpret_cast<const float4*>(yp + 4);
  float vv[8] = {v0.x, v0.y, v0.z, v0.w, v1.x, v1.y, v1.z, v1.w};
  float s = 0.f, s2 = 0.f;
#pragma unroll
  for (int j = 0; j < 8; ++j) { s += vv[j]; s2 += vv[j] * vv[j]; }
  for (int mk = 1; mk < 64; mk <<= 1) {
    s += __shfl_xor(s, mk, 64);
    s2 += __shfl_xor(s2, mk, 64);
  }
  const float mu = s * (1.0f / Dm);
  const float var = s2 * (1.0f / Dm) - mu * mu;
  const float inv = rsqrtf(var + 1e-6f);
  float* op = out + (size_t)row * Dm + lane * 8;
  const float* gp = g + lane * 8;
  const float* bp = be + lane * 8;
#pragma unroll
  for (int j = 0; j < 8; ++j) op[j] = (vv[j] - mu) * inv * gp[j] + bp[j];
}

// ------------------------------------------------------------------------------
extern "C" void kernel_launch(void* const* d_in, const int* in_sizes, int n_in,
                              void* d_out, int out_size, void* d_ws, size_t ws_size,
                              hipStream_t stream) {
  const float* q   = (const float*)d_in[0];
  const float* k   = (const float*)d_in[1];
  const float* v   = (const float*)d_in[2];
  const float* Wq  = (const float*)d_in[3];
  const float* Wk  = (const float*)d_in[4];
  const float* Wv  = (const float*)d_in[5];
  const float* Wfc = (const float*)d_in[6];
  const float* rel = (const float*)d_in[7];
  const float* gam = (const float*)d_in[8];
  const float* bet = (const float*)d_in[9];

  char* ws = (char*)d_ws;
  size_t off = 0;
  auto take = [&](size_t bytes) {
    char* p = ws + off;
    off += (bytes + 255) & ~(size_t)255;
    return p;
  };
  bf16_t* wqb  = (bf16_t*)take((size_t)Dm * Dm * 2);
  bf16_t* wkb  = (bf16_t*)take((size_t)Dm * Dm * 2);
  bf16_t* wvb  = (bf16_t*)take((size_t)Dm * Dm * 2);
  bf16_t* wfcb = (bf16_t*)take((size_t)Dm * Dm * 2);
  bf16_t* relb = (bf16_t*)take((size_t)NREL * DKd * 2);
  bf16_t* qb   = (bf16_t*)take((size_t)MTOK * Dm * 2);
  bf16_t* kb   = (bf16_t*)take((size_t)MTOK * Dm * 2);
  bf16_t* vb   = (bf16_t*)take((size_t)MTOK * Dm * 2);
  bf16_t* Qhp  = (bf16_t*)take((size_t)MTOK * Dm * 2);
  bf16_t* Khp  = (bf16_t*)take((size_t)MTOK * Dm * 2);
  bf16_t* Vtp  = (bf16_t*)take((size_t)MTOK * Dm * 2);
  bf16_t* posd = (bf16_t*)take((size_t)Bz * Hh * Lseq * NREL * 2);
  bf16_t* attnb= (bf16_t*)take((size_t)MTOK * Dm * 2);
  float*  yf   = (float*)take((size_t)MTOK * Dm * 4);

  auto cast = [&](const float* s, bf16_t* d, int n) {
    k_cast<<<dim3((n / 4 + 255) / 256), 256, 0, stream>>>(s, d, n);
  };
  cast(q, qb, MTOK * Dm);
  cast(k, kb, MTOK * Dm);
  cast(v, vb, MTOK * Dm);
  cast(Wq, wqb, Dm * Dm);
  cast(Wk, wkb, Dm * Dm);
  cast(Wv, wvb, Dm * Dm);
  cast(Wfc, wfcb, Dm * Dm);
  cast(rel, relb, NREL * DKd);

  dim3 gg(Dm / 64, MTOK / 64);
  k_gemm512<0><<<gg, 256, 0, stream>>>(qb, wqb, Qhp, nullptr, nullptr);
  k_gemm512<0><<<gg, 256, 0, stream>>>(kb, wkb, Khp, nullptr, nullptr);
  k_gemm512<1><<<gg, 256, 0, stream>>>(vb, wvb, Vtp, nullptr, nullptr);
  k_posdot<<<dim3(13, MTOK / 64), 256, 0, stream>>>(Qhp, relb, posd);
  k_attn<<<dim3(64 * 64), 64, 0, stream>>>(Qhp, Khp, Vtp, posd, attnb);
  k_gemm512<2><<<gg, 256, 0, stream>>>(attnb, wfcb, nullptr, yf, q);
  k_ln<<<dim3(MTOK / 4), 256, 0, stream>>>(yf, gam, bet, (float*)d_out);
}

// Round 4
// 278.681 us; speedup vs baseline: 1.0418x; 1.0418x over previous
//
#include <hip/hip_runtime.h>
#include <hip/hip_bf16.h>

typedef __bf16 bf16_t;
typedef __bf16 bf16x8 __attribute__((ext_vector_type(8)));
typedef float f32x4 __attribute__((ext_vector_type(4)));

constexpr int Bz = 8, Lseq = 1024, Dm = 512, Hh = 8, DKd = 64;
constexpr int MTOK = Bz * Lseq;   // 8192 tokens
constexpr int NREL = 201;

// pos pre-scale: 0.125 (1/sqrt(dk)) * log2(e), folded so p = exp2(st*C + pos)
#define POS_C 0.18033688011112042f

__device__ inline float fexp2(float x) {
#if __has_builtin(__builtin_amdgcn_exp2f)
  return __builtin_amdgcn_exp2f(x);
#else
  return exp2f(x);
#endif
}
__device__ inline float b2f(unsigned short u) {
  return __builtin_bit_cast(float, (unsigned)u << 16);
}
__device__ inline unsigned pack2(float a, float b) {
  unsigned short ua = __builtin_bit_cast(unsigned short, (bf16_t)a);
  unsigned short ub = __builtin_bit_cast(unsigned short, (bf16_t)b);
  return (unsigned)ua | ((unsigned)ub << 16);
}

// ---------------- fp32 -> bf16 cast ----------------
__global__ __launch_bounds__(256) void k_cast(const float* __restrict__ s,
                                              bf16_t* __restrict__ d, int n) {
  int i = (blockIdx.x * 256 + threadIdx.x) * 4;
  if (i < n) {
    float4 v = *reinterpret_cast<const float4*>(s + i);
    d[i + 0] = (bf16_t)v.x;
    d[i + 1] = (bf16_t)v.y;
    d[i + 2] = (bf16_t)v.z;
    d[i + 3] = (bf16_t)v.w;
  }
}

// ---------------- y = A @ W^T  (A:[8192][512] bf16, W:[512][512] bf16) --------
// MODE 0: store bf16 head-major   out[(b*8+h)*1024+q][64]   (Qh / Kh)
// MODE 1: store bf16 head-transposed out[(b*8+h)*64+d][1024] (Vt)
// MODE 2: store fp32 row-major + residual add (pre-LN x)
template <int MODE>
__global__ __launch_bounds__(256) void k_gemm512(const bf16_t* __restrict__ A,
                                                 const bf16_t* __restrict__ W,
                                                 bf16_t* __restrict__ outb,
                                                 float* __restrict__ outf,
                                                 const float* __restrict__ resid) {
  const int lane = threadIdx.x & 63, w = threadIdx.x >> 6;
  const int lr = lane & 15, lg = lane >> 4;
  const int Rbase = blockIdx.y * 64 + (w >> 1) * 32;
  const int Cbase = blockIdx.x * 64 + (w & 1) * 32;

  f32x4 acc[2][2] = {};
  for (int k0 = 0; k0 < Dm; k0 += 32) {
    bf16x8 af[2], wf[2];
#pragma unroll
    for (int i = 0; i < 2; ++i)
      af[i] = *reinterpret_cast<const bf16x8*>(A + (size_t)(Rbase + i * 16 + lr) * Dm + k0 + lg * 8);
#pragma unroll
    for (int j = 0; j < 2; ++j)
      wf[j] = *reinterpret_cast<const bf16x8*>(W + (size_t)(Cbase + j * 16 + lr) * Dm + k0 + lg * 8);
#pragma unroll
    for (int i = 0; i < 2; ++i)
#pragma unroll
      for (int j = 0; j < 2; ++j)
        acc[i][j] = __builtin_amdgcn_mfma_f32_16x16x32_bf16(af[i], wf[j], acc[i][j], 0, 0, 0);
  }
#pragma unroll
  for (int i = 0; i < 2; ++i)
#pragma unroll
    for (int j = 0; j < 2; ++j)
#pragma unroll
      for (int r = 0; r < 4; ++r) {
        const int gr = Rbase + i * 16 + lg * 4 + r;  // token row
        const int gc = Cbase + j * 16 + lr;          // output col
        const float vv = acc[i][j][r];
        if (MODE == 0) {
          const int bb = gr >> 10, qq = gr & 1023, hh = gc >> 6, dd = gc & 63;
          outb[(((size_t)(bb * Hh + hh)) * Lseq + qq) * DKd + dd] = (bf16_t)vv;
        } else if (MODE == 1) {
          const int bb = gr >> 10, qq = gr & 1023, hh = gc >> 6, dd = gc & 63;
          outb[(((size_t)(bb * Hh + hh)) * DKd + dd) * Lseq + qq] = (bf16_t)vv;
        } else {
          const size_t idx = (size_t)gr * Dm + gc;
          outf[idx] = vv + resid[idx];
        }
      }
}

// ---------------- pos_dot, stored REVERSED and PRE-SCALED ---------------------
// pdr[q][j] = POS_C * (Qh[q] . rel_emb[200-j]);  in-band j = k - q + 100.
__global__ __launch_bounds__(256) void k_posdot(const bf16_t* __restrict__ Qh,
                                                const bf16_t* __restrict__ relb,
                                                bf16_t* __restrict__ posd) {
  const int lane = threadIdx.x & 63, w = threadIdx.x >> 6;
  const int lr = lane & 15, lg = lane >> 4;
  const int m0 = blockIdx.y * 64 + w * 16;
  const int n0 = blockIdx.x * 16;
  const int r = n0 + lr;

  bf16x8 a0 = *reinterpret_cast<const bf16x8*>(Qh + (size_t)(m0 + lr) * DKd + lg * 8);
  bf16x8 a1 = *reinterpret_cast<const bf16x8*>(Qh + (size_t)(m0 + lr) * DKd + 32 + lg * 8);
  bf16x8 b0 = {}, b1 = {};
  if (r < NREL) {
    b0 = *reinterpret_cast<const bf16x8*>(relb + (size_t)r * DKd + lg * 8);
    b1 = *reinterpret_cast<const bf16x8*>(relb + (size_t)r * DKd + 32 + lg * 8);
  }
  f32x4 acc = {};
  acc = __builtin_amdgcn_mfma_f32_16x16x32_bf16(a0, b0, acc, 0, 0, 0);
  acc = __builtin_amdgcn_mfma_f32_16x16x32_bf16(a1, b1, acc, 0, 0, 0);
#pragma unroll
  for (int rr = 0; rr < 4; ++rr) {
    const int row = m0 + lg * 4 + rr;
    const int col = n0 + lr;
    if (col < NREL)
      posd[(size_t)row * NREL + (200 - col)] = (bf16_t)(acc[rr] * POS_C);
  }
}

// ---------------- flash attention, no-max softmax, swapped QK^T ---------------
// Block = 4 waves = 2 (bh, 32-q-tile) units x 2 k-halves. No barrier in loop.
__global__ __launch_bounds__(256, 4) void k_attn(const bf16_t* __restrict__ Qh,
                                                 const bf16_t* __restrict__ Kh,
                                                 const bf16_t* __restrict__ Vt,
                                                 const bf16_t* __restrict__ posd,
                                                 bf16_t* __restrict__ attnb) {
  __shared__ unsigned Pl[4][2][16][20];   // per-wave P transpose, padded rows
  __shared__ float Ml[2][64][35];         // k-split merge buffer

  const int tid = threadIdx.x;
  const int wv = tid >> 6, lane = tid & 63;
  const int lr = lane & 15, lg = lane >> 4;
  const int pair = wv >> 1, kh = wv & 1;
  const int gid = blockIdx.x * 2 + pair;      // 2048 units
  const int bh = gid >> 5;
  const int qb = (gid & 31) << 5;             // 32-row q tile

  const bf16_t* Qp = Qh + ((size_t)bh * Lseq + qb) * DKd;
  const bf16_t* Kp = Kh + (size_t)bh * Lseq * DKd;
  const bf16_t* Vp = Vt + (size_t)bh * DKd * Lseq;
  const unsigned short* pu =
      (const unsigned short*)posd + ((size_t)bh * Lseq + qb) * NREL;

  // per-lane pos row bases + band-edge constants (already scaled by POS_C)
  const unsigned short* rb[2] = {pu + (size_t)lr * NREL,
                                 pu + (size_t)(16 + lr) * NREL};
  float pe0[2], pe200[2];
#pragma unroll
  for (int t = 0; t < 2; ++t) {
    pe0[t] = b2f(rb[t][0]);       // k <= q-100 side
    pe200[t] = b2f(rb[t][200]);   // k >= q+100 side
  }

  // Q fragments (B-operand: lane&15 = q col, lg*8 = d dims, h = d-half)
  bf16x8 qf[2][2];
#pragma unroll
  for (int t = 0; t < 2; ++t)
#pragma unroll
    for (int h = 0; h < 2; ++h)
      qf[t][h] = *reinterpret_cast<const bf16x8*>(Qp + (size_t)(t * 16 + lr) * DKd + h * 32 + lg * 8);

  f32x4 Oacc[2][4] = {};
  float psum[2] = {0.f, 0.f};
  const int ldelta = lg * 4 - lr;

#pragma unroll 2
  for (int k0 = kh * 512; k0 < kh * 512 + 512; k0 += 32) {
    // K fragments (A-operand: lane&15 = k row, lg*8 = d dims)
    bf16x8 kf[2][2];
#pragma unroll
    for (int u = 0; u < 2; ++u)
#pragma unroll
      for (int h = 0; h < 2; ++h)
        kf[u][h] = *reinterpret_cast<const bf16x8*>(Kp + (size_t)(k0 + u * 16 + lr) * DKd + h * 32 + lg * 8);

#pragma unroll
    for (int t = 0; t < 2; ++t) {
      const int Qt = qb + t * 16;
      f32x4 st[2];
#pragma unroll
      for (int u = 0; u < 2; ++u) {
        f32x4 a = {};
        a = __builtin_amdgcn_mfma_f32_16x16x32_bf16(kf[u][0], qf[t][0], a, 0, 0, 0);
        a = __builtin_amdgcn_mfma_f32_16x16x32_bf16(kf[u][1], qf[t][1], a, 0, 0, 0);
        st[u] = a;  // element: q = Qt+lr (col), k = k0+u*16+lg*4+r (row)
      }
      float p[2][4];
      if (k0 + 131 <= Qt) {            // whole step below band: pos = pdr[q][0]
#pragma unroll
        for (int u = 0; u < 2; ++u)
#pragma unroll
          for (int r = 0; r < 4; ++r)
            p[u][r] = fexp2(fmaf(st[u][r], POS_C, pe0[t]));
      } else if (k0 >= Qt + 115) {     // whole step above band: pos = pdr[q][200]
#pragma unroll
        for (int u = 0; u < 2; ++u)
#pragma unroll
          for (int r = 0; r < 4; ++r)
            p[u][r] = fexp2(fmaf(st[u][r], POS_C, pe200[t]));
      } else {                         // in-band: clamped gather (contiguous j)
#pragma unroll
        for (int u = 0; u < 2; ++u) {
          const int jb = k0 + u * 16 + 100 - Qt + ldelta;
#pragma unroll
          for (int r = 0; r < 4; ++r) {
            int j = jb + r;
            j = j < 0 ? 0 : (j > 200 ? 200 : j);
            p[u][r] = fexp2(fmaf(st[u][r], POS_C, b2f(rb[t][j])));
          }
        }
      }
#pragma unroll
      for (int u = 0; u < 2; ++u)
#pragma unroll
        for (int r = 0; r < 4; ++r) psum[t] += p[u][r];
      // pack to bf16, wave-private LDS transpose (D-layout -> B-frag layout)
#pragma unroll
      for (int u = 0; u < 2; ++u) {
        uint2 pk;
        pk.x = pack2(p[u][0], p[u][1]);
        pk.y = pack2(p[u][2], p[u][3]);
        *reinterpret_cast<uint2*>(&Pl[wv][t][lr][u * 8 + lg * 2]) = pk;
      }
    }
    // PV: A = Vt fragment, B = P fragment read back from LDS
    bf16x8 pb[2];
#pragma unroll
    for (int t = 0; t < 2; ++t)
      pb[t] = *reinterpret_cast<const bf16x8*>(&Pl[wv][t][lr][lg * 4]);
#pragma unroll
    for (int f = 0; f < 4; ++f) {
      bf16x8 vf = *reinterpret_cast<const bf16x8*>(Vp + (size_t)(f * 16 + lr) * Lseq + k0 + lg * 8);
#pragma unroll
      for (int t = 0; t < 2; ++t)
        Oacc[t][f] = __builtin_amdgcn_mfma_f32_16x16x32_bf16(vf, pb[t], Oacc[t][f], 0, 0, 0);
    }
  }

  // ---- merge the two k-halves (no-max partials combine by pure addition) ----
  if (kh) {
    float* m = Ml[pair][lane];
#pragma unroll
    for (int t = 0; t < 2; ++t)
#pragma unroll
      for (int f = 0; f < 4; ++f)
#pragma unroll
        for (int r = 0; r < 4; ++r) m[t * 16 + f * 4 + r] = Oacc[t][f][r];
    m[32] = psum[0];
    m[33] = psum[1];
  }
  __syncthreads();
  if (!kh) {
    const float* m = Ml[pair][lane];
#pragma unroll
    for (int t = 0; t < 2; ++t)
#pragma unroll
      for (int f = 0; f < 4; ++f)
#pragma unroll
        for (int r = 0; r < 4; ++r) Oacc[t][f][r] += m[t * 16 + f * 4 + r];
    const int gb = bh >> 3, hh = bh & 7;
#pragma unroll
    for (int t = 0; t < 2; ++t) {
      float s = psum[t] + m[32 + t];
      s += __shfl_xor(s, 16);
      s += __shfl_xor(s, 32);
      const float inv = 1.0f / s;
      const int qg = qb + t * 16 + lr;
#pragma unroll
      for (int f = 0; f < 4; ++f) {
        uint2 ov;
        ov.x = pack2(Oacc[t][f][0] * inv, Oacc[t][f][1] * inv);
        ov.y = pack2(Oacc[t][f][2] * inv, Oacc[t][f][3] * inv);
        *reinterpret_cast<uint2*>(attnb + ((size_t)(gb * Lseq + qg)) * Dm + hh * DKd + f * 16 + lg * 4) = ov;
      }
    }
  }
}

// ---------------- row LayerNorm over D=512 ------------------------------------
__global__ __launch_bounds__(256) void k_ln(const float* __restrict__ y,
                                            const float* __restrict__ g,
                                            const float* __restrict__ be,
                                            float* __restrict__ out) {
  const int row = blockIdx.x * 4 + (threadIdx.x >> 6);
  const int lane = threadIdx.x & 63;
  const float* yp = y + (size_t)row * Dm + lane * 8;
  float4 v0 = *reinterpret_cast<const float4*>(yp);
  float4 v1 = *reinterpret_cast<const float4*>(yp + 4);
  float vv[8] = {v0.x, v0.y, v0.z, v0.w, v1.x, v1.y, v1.z, v1.w};
  float s = 0.f, s2 = 0.f;
#pragma unroll
  for (int j = 0; j < 8; ++j) { s += vv[j]; s2 += vv[j] * vv[j]; }
  for (int mk = 1; mk < 64; mk <<= 1) {
    s += __shfl_xor(s, mk, 64);
    s2 += __shfl_xor(s2, mk, 64);
  }
  const float mu = s * (1.0f / Dm);
  const float var = s2 * (1.0f / Dm) - mu * mu;
  const float inv = rsqrtf(var + 1e-6f);
  float* op = out + (size_t)row * Dm + lane * 8;
  const float* gp = g + lane * 8;
  const float* bp = be + lane * 8;
#pragma unroll
  for (int j = 0; j < 8; ++j) op[j] = (vv[j] - mu) * inv * gp[j] + bp[j];
}

// ------------------------------------------------------------------------------
extern "C" void kernel_launch(void* const* d_in, const int* in_sizes, int n_in,
                              void* d_out, int out_size, void* d_ws, size_t ws_size,
                              hipStream_t stream) {
  const float* q   = (const float*)d_in[0];
  const float* k   = (const float*)d_in[1];
  const float* v   = (const float*)d_in[2];
  const float* Wq  = (const float*)d_in[3];
  const float* Wk  = (const float*)d_in[4];
  const float* Wv  = (const float*)d_in[5];
  const float* Wfc = (const float*)d_in[6];
  const float* rel = (const float*)d_in[7];
  const float* gam = (const float*)d_in[8];
  const float* bet = (const float*)d_in[9];

  char* ws = (char*)d_ws;
  size_t off = 0;
  auto take = [&](size_t bytes) {
    char* p = ws + off;
    off += (bytes + 255) & ~(size_t)255;
    return p;
  };
  bf16_t* wqb  = (bf16_t*)take((size_t)Dm * Dm * 2);
  bf16_t* wkb  = (bf16_t*)take((size_t)Dm * Dm * 2);
  bf16_t* wvb  = (bf16_t*)take((size_t)Dm * Dm * 2);
  bf16_t* wfcb = (bf16_t*)take((size_t)Dm * Dm * 2);
  bf16_t* relb = (bf16_t*)take((size_t)NREL * DKd * 2);
  bf16_t* qb   = (bf16_t*)take((size_t)MTOK * Dm * 2);
  bf16_t* kb   = (bf16_t*)take((size_t)MTOK * Dm * 2);
  bf16_t* vb   = (bf16_t*)take((size_t)MTOK * Dm * 2);
  bf16_t* Qhp  = (bf16_t*)take((size_t)MTOK * Dm * 2);
  bf16_t* Khp  = (bf16_t*)take((size_t)MTOK * Dm * 2);
  bf16_t* Vtp  = (bf16_t*)take((size_t)MTOK * Dm * 2);
  bf16_t* posd = (bf16_t*)take((size_t)Bz * Hh * Lseq * NREL * 2);
  bf16_t* attnb= (bf16_t*)take((size_t)MTOK * Dm * 2);
  float*  yf   = (float*)take((size_t)MTOK * Dm * 4);

  auto cast = [&](const float* s, bf16_t* d, int n) {
    k_cast<<<dim3((n / 4 + 255) / 256), 256, 0, stream>>>(s, d, n);
  };
  cast(q, qb, MTOK * Dm);
  cast(k, kb, MTOK * Dm);
  cast(v, vb, MTOK * Dm);
  cast(Wq, wqb, Dm * Dm);
  cast(Wk, wkb, Dm * Dm);
  cast(Wv, wvb, Dm * Dm);
  cast(Wfc, wfcb, Dm * Dm);
  cast(rel, relb, NREL * DKd);

  dim3 gg(Dm / 64, MTOK / 64);
  k_gemm512<0><<<gg, 256, 0, stream>>>(qb, wqb, Qhp, nullptr, nullptr);
  k_gemm512<0><<<gg, 256, 0, stream>>>(kb, wkb, Khp, nullptr, nullptr);
  k_gemm512<1><<<gg, 256, 0, stream>>>(vb, wvb, Vtp, nullptr, nullptr);
  k_posdot<<<dim3(13, MTOK / 64), 256, 0, stream>>>(Qhp, relb, posd);
  k_attn<<<dim3(1024), 256, 0, stream>>>(Qhp, Khp, Vtp, posd, attnb);
  k_gemm512<2><<<gg, 256, 0, stream>>>(attnb, wfcb, nullptr, yf, q);
  k_ln<<<dim3(MTOK / 4), 256, 0, stream>>>(yf, gam, bet, (float*)d_out);
}

// Round 7
// 264.044 us; speedup vs baseline: 1.0996x; 1.0554x over previous
//
#include <hip/hip_runtime.h>
#include <hip/hip_bf16.h>

typedef __bf16 bf16_t;
typedef __bf16 bf16x8 __attribute__((ext_vector_type(8)));
typedef float f32x4 __attribute__((ext_vector_type(4)));

constexpr int Bz = 8, Lseq = 1024, Dm = 512, Hh = 8, DKd = 64;
constexpr int MTOK = Bz * Lseq;   // 8192 tokens
constexpr int NREL = 201;

// pos pre-scale: 0.125 (1/sqrt(dk)) * log2(e), folded so p = exp2(st*C + pos)
#define POS_C 0.18033688011112042f

__device__ inline float fexp2(float x) {
#if __has_builtin(__builtin_amdgcn_exp2f)
  return __builtin_amdgcn_exp2f(x);
#else
  return exp2f(x);
#endif
}
__device__ inline float b2f(unsigned short u) {
  return __builtin_bit_cast(float, (unsigned)u << 16);
}
__device__ inline unsigned pack2(float a, float b) {
  unsigned short ua = __builtin_bit_cast(unsigned short, (bf16_t)a);
  unsigned short ub = __builtin_bit_cast(unsigned short, (bf16_t)b);
  return (unsigned)ua | ((unsigned)ub << 16);
}

// ---------------- fp32 -> bf16 cast ----------------
__global__ __launch_bounds__(256) void k_cast(const float* __restrict__ s,
                                              bf16_t* __restrict__ d, int n) {
  int i = (blockIdx.x * 256 + threadIdx.x) * 4;
  if (i < n) {
    float4 v = *reinterpret_cast<const float4*>(s + i);
    d[i + 0] = (bf16_t)v.x;
    d[i + 1] = (bf16_t)v.y;
    d[i + 2] = (bf16_t)v.z;
    d[i + 3] = (bf16_t)v.w;
  }
}

// ---------------- y = A @ W^T  (A:[8192][512] bf16, W:[512][512] bf16) --------
// MODE 0: store bf16 head-major   out[(b*8+h)*1024+q][64]   (Qh / Kh)
// MODE 1: store bf16 head-transposed out[(b*8+h)*64+d][1024] (Vt)
// MODE 2: store fp32 row-major + residual add (pre-LN x)
template <int MODE>
__global__ __launch_bounds__(256) void k_gemm512(const bf16_t* __restrict__ A,
                                                 const bf16_t* __restrict__ W,
                                                 bf16_t* __restrict__ outb,
                                                 float* __restrict__ outf,
                                                 const float* __restrict__ resid) {
  const int lane = threadIdx.x & 63, w = threadIdx.x >> 6;
  const int lr = lane & 15, lg = lane >> 4;
  const int Rbase = blockIdx.y * 64 + (w >> 1) * 32;
  const int Cbase = blockIdx.x * 64 + (w & 1) * 32;

  f32x4 acc[2][2] = {};
  for (int k0 = 0; k0 < Dm; k0 += 32) {
    bf16x8 af[2], wf[2];
#pragma unroll
    for (int i = 0; i < 2; ++i)
      af[i] = *reinterpret_cast<const bf16x8*>(A + (size_t)(Rbase + i * 16 + lr) * Dm + k0 + lg * 8);
#pragma unroll
    for (int j = 0; j < 2; ++j)
      wf[j] = *reinterpret_cast<const bf16x8*>(W + (size_t)(Cbase + j * 16 + lr) * Dm + k0 + lg * 8);
#pragma unroll
    for (int i = 0; i < 2; ++i)
#pragma unroll
      for (int j = 0; j < 2; ++j)
        acc[i][j] = __builtin_amdgcn_mfma_f32_16x16x32_bf16(af[i], wf[j], acc[i][j], 0, 0, 0);
  }
#pragma unroll
  for (int i = 0; i < 2; ++i)
#pragma unroll
    for (int j = 0; j < 2; ++j)
#pragma unroll
      for (int r = 0; r < 4; ++r) {
        const int gr = Rbase + i * 16 + lg * 4 + r;  // token row
        const int gc = Cbase + j * 16 + lr;          // output col
        const float vv = acc[i][j][r];
        if (MODE == 0) {
          const int bb = gr >> 10, qq = gr & 1023, hh = gc >> 6, dd = gc & 63;
          outb[(((size_t)(bb * Hh + hh)) * Lseq + qq) * DKd + dd] = (bf16_t)vv;
        } else if (MODE == 1) {
          const int bb = gr >> 10, qq = gr & 1023, hh = gc >> 6, dd = gc & 63;
          outb[(((size_t)(bb * Hh + hh)) * DKd + dd) * Lseq + qq] = (bf16_t)vv;
        } else {
          const size_t idx = (size_t)gr * Dm + gc;
          outf[idx] = vv + resid[idx];
        }
      }
}

// ---------------- pos_dot, stored REVERSED and PRE-SCALED ---------------------
// pdr[q][j] = POS_C * (Qh[q] . rel_emb[200-j]);  in-band j = k - q + 100.
__global__ __launch_bounds__(256) void k_posdot(const bf16_t* __restrict__ Qh,
                                                const bf16_t* __restrict__ relb,
                                                bf16_t* __restrict__ posd) {
  const int lane = threadIdx.x & 63, w = threadIdx.x >> 6;
  const int lr = lane & 15, lg = lane >> 4;
  const int m0 = blockIdx.y * 64 + w * 16;
  const int n0 = blockIdx.x * 16;
  const int r = n0 + lr;

  bf16x8 a0 = *reinterpret_cast<const bf16x8*>(Qh + (size_t)(m0 + lr) * DKd + lg * 8);
  bf16x8 a1 = *reinterpret_cast<const bf16x8*>(Qh + (size_t)(m0 + lr) * DKd + 32 + lg * 8);
  bf16x8 b0 = {}, b1 = {};
  if (r < NREL) {
    b0 = *reinterpret_cast<const bf16x8*>(relb + (size_t)r * DKd + lg * 8);
    b1 = *reinterpret_cast<const bf16x8*>(relb + (size_t)r * DKd + 32 + lg * 8);
  }
  f32x4 acc = {};
  acc = __builtin_amdgcn_mfma_f32_16x16x32_bf16(a0, b0, acc, 0, 0, 0);
  acc = __builtin_amdgcn_mfma_f32_16x16x32_bf16(a1, b1, acc, 0, 0, 0);
#pragma unroll
  for (int rr = 0; rr < 4; ++rr) {
    const int row = m0 + lg * 4 + rr;
    const int col = n0 + lr;
    if (col < NREL)
      posd[(size_t)row * NREL + (200 - col)] = (bf16_t)(acc[rr] * POS_C);
  }
}

// ---------------- flash attention, no-max softmax, swapped QK^T ---------------
// Block = 4 waves = 2 (bh, 32-q-tile) units x 2 k-halves. No barrier in loop.
// XCD-chunked block swizzle: works [128x,128x+128) -> XCD x, so each XCD's
// private L2 sees only bh in [8x, 8x+8) (2 MB of K/V, fits 4 MB L2).
__global__ __launch_bounds__(256, 4) void k_attn(const bf16_t* __restrict__ Qh,
                                                 const bf16_t* __restrict__ Kh,
                                                 const bf16_t* __restrict__ Vt,
                                                 const bf16_t* __restrict__ posd,
                                                 bf16_t* __restrict__ attnb) {
  __shared__ unsigned Pl[4][2][16][20];   // per-wave P transpose, padded rows
  __shared__ float Ml[2][64][35];         // k-split merge buffer

  const int tid = threadIdx.x;
  const int wv = tid >> 6, lane = tid & 63;
  const int lr = lane & 15, lg = lane >> 4;
  const int pair = wv >> 1, kh = wv & 1;
  // bijective chunked XCD swizzle (nwg=1024, 1024%8==0)
  const int bid = ((blockIdx.x & 7) << 7) | (blockIdx.x >> 3);
  const int gid = bid * 2 + pair;             // 2048 units
  const int bh = gid >> 5;
  const int qb = (gid & 31) << 5;             // 32-row q tile

  const bf16_t* Qp = Qh + ((size_t)bh * Lseq + qb) * DKd;
  const bf16_t* Kp = Kh + (size_t)bh * Lseq * DKd;
  const bf16_t* Vp = Vt + (size_t)bh * DKd * Lseq;
  const unsigned short* pu =
      (const unsigned short*)posd + ((size_t)bh * Lseq + qb) * NREL;

  // per-lane pos row bases + band-edge constants (already scaled by POS_C)
  const unsigned short* rb[2] = {pu + (size_t)lr * NREL,
                                 pu + (size_t)(16 + lr) * NREL};
  float pe0[2], pe200[2];
#pragma unroll
  for (int t = 0; t < 2; ++t) {
    pe0[t] = b2f(rb[t][0]);       // k <= q-100 side
    pe200[t] = b2f(rb[t][200]);   // k >= q+100 side
  }

  // Q fragments (B-operand: lane&15 = q col, lg*8 = d dims, h = d-half)
  bf16x8 qf[2][2];
#pragma unroll
  for (int t = 0; t < 2; ++t)
#pragma unroll
    for (int h = 0; h < 2; ++h)
      qf[t][h] = *reinterpret_cast<const bf16x8*>(Qp + (size_t)(t * 16 + lr) * DKd + h * 32 + lg * 8);

  f32x4 Oacc[2][4] = {};
  float psum[2] = {0.f, 0.f};
  const int ldelta = lg * 4 - lr;

#pragma unroll 2
  for (int k0 = kh * 512; k0 < kh * 512 + 512; k0 += 32) {
    // K fragments (A-operand: lane&15 = k row, lg*8 = d dims)
    bf16x8 kf[2][2];
#pragma unroll
    for (int u = 0; u < 2; ++u)
#pragma unroll
      for (int h = 0; h < 2; ++h)
        kf[u][h] = *reinterpret_cast<const bf16x8*>(Kp + (size_t)(k0 + u * 16 + lr) * DKd + h * 32 + lg * 8);

#pragma unroll
    for (int t = 0; t < 2; ++t) {
      const int Qt = qb + t * 16;
      f32x4 st[2];
#pragma unroll
      for (int u = 0; u < 2; ++u) {
        f32x4 a = {};
        a = __builtin_amdgcn_mfma_f32_16x16x32_bf16(kf[u][0], qf[t][0], a, 0, 0, 0);
        a = __builtin_amdgcn_mfma_f32_16x16x32_bf16(kf[u][1], qf[t][1], a, 0, 0, 0);
        st[u] = a;  // element: q = Qt+lr (col), k = k0+u*16+lg*4+r (row)
      }
      float p[2][4];
      if (k0 + 131 <= Qt) {            // whole step below band: pos = pdr[q][0]
#pragma unroll
        for (int u = 0; u < 2; ++u)
#pragma unroll
          for (int r = 0; r < 4; ++r)
            p[u][r] = fexp2(fmaf(st[u][r], POS_C, pe0[t]));
      } else if (k0 >= Qt + 115) {     // whole step above band: pos = pdr[q][200]
#pragma unroll
        for (int u = 0; u < 2; ++u)
#pragma unroll
          for (int r = 0; r < 4; ++r)
            p[u][r] = fexp2(fmaf(st[u][r], POS_C, pe200[t]));
      } else {                         // in-band: clamped gather (contiguous j)
#pragma unroll
        for (int u = 0; u < 2; ++u) {
          const int jb = k0 + u * 16 + 100 - Qt + ldelta;
#pragma unroll
          for (int r = 0; r < 4; ++r) {
            int j = jb + r;
            j = j < 0 ? 0 : (j > 200 ? 200 : j);
            p[u][r] = fexp2(fmaf(st[u][r], POS_C, b2f(rb[t][j])));
          }
        }
      }
#pragma unroll
      for (int u = 0; u < 2; ++u)
#pragma unroll
        for (int r = 0; r < 4; ++r) psum[t] += p[u][r];
      // pack to bf16, wave-private LDS transpose (D-layout -> B-frag layout)
#pragma unroll
      for (int u = 0; u < 2; ++u) {
        uint2 pk;
        pk.x = pack2(p[u][0], p[u][1]);
        pk.y = pack2(p[u][2], p[u][3]);
        *reinterpret_cast<uint2*>(&Pl[wv][t][lr][u * 8 + lg * 2]) = pk;
      }
    }
    // PV: A = Vt fragment, B = P fragment read back from LDS
    bf16x8 pb[2];
#pragma unroll
    for (int t = 0; t < 2; ++t)
      pb[t] = *reinterpret_cast<const bf16x8*>(&Pl[wv][t][lr][lg * 4]);
#pragma unroll
    for (int f = 0; f < 4; ++f) {
      bf16x8 vf = *reinterpret_cast<const bf16x8*>(Vp + (size_t)(f * 16 + lr) * Lseq + k0 + lg * 8);
#pragma unroll
      for (int t = 0; t < 2; ++t)
        Oacc[t][f] = __builtin_amdgcn_mfma_f32_16x16x32_bf16(vf, pb[t], Oacc[t][f], 0, 0, 0);
    }
  }

  // ---- merge the two k-halves (no-max partials combine by pure addition) ----
  if (kh) {
    float* m = Ml[pair][lane];
#pragma unroll
    for (int t = 0; t < 2; ++t)
#pragma unroll
      for (int f = 0; f < 4; ++f)
#pragma unroll
        for (int r = 0; r < 4; ++r) m[t * 16 + f * 4 + r] = Oacc[t][f][r];
    m[32] = psum[0];
    m[33] = psum[1];
  }
  __syncthreads();
  if (!kh) {
    const float* m = Ml[pair][lane];
#pragma unroll
    for (int t = 0; t < 2; ++t)
#pragma unroll
      for (int f = 0; f < 4; ++f)
#pragma unroll
        for (int r = 0; r < 4; ++r) Oacc[t][f][r] += m[t * 16 + f * 4 + r];
    const int gb = bh >> 3, hh = bh & 7;
#pragma unroll
    for (int t = 0; t < 2; ++t) {
      float s = psum[t] + m[32 + t];
      s += __shfl_xor(s, 16);
      s += __shfl_xor(s, 32);
      const float inv = 1.0f / s;
      const int qg = qb + t * 16 + lr;
#pragma unroll
      for (int f = 0; f < 4; ++f) {
        uint2 ov;
        ov.x = pack2(Oacc[t][f][0] * inv, Oacc[t][f][1] * inv);
        ov.y = pack2(Oacc[t][f][2] * inv, Oacc[t][f][3] * inv);
        *reinterpret_cast<uint2*>(attnb + ((size_t)(gb * Lseq + qg)) * Dm + hh * DKd + f * 16 + lg * 4) = ov;
      }
    }
  }
}

// ---------------- row LayerNorm over D=512 ------------------------------------
__global__ __launch_bounds__(256) void k_ln(const float* __restrict__ y,
                                            const float* __restrict__ g,
                                            const float* __restrict__ be,
                                            float* __restrict__ out) {
  const int row = blockIdx.x * 4 + (threadIdx.x >> 6);
  const int lane = threadIdx.x & 63;
  const float* yp = y + (size_t)row * Dm + lane * 8;
  float4 v0 = *reinterpret_cast<const float4*>(yp);
  float4 v1 = *reinterpret_cast<const float4*>(yp + 4);
  float vv[8] = {v0.x, v0.y, v0.z, v0.w, v1.x, v1.y, v1.z, v1.w};
  float s = 0.f, s2 = 0.f;
#pragma unroll
  for (int j = 0; j < 8; ++j) { s += vv[j]; s2 += vv[j] * vv[j]; }
  for (int mk = 1; mk < 64; mk <<= 1) {
    s += __shfl_xor(s, mk, 64);
    s2 += __shfl_xor(s2, mk, 64);
  }
  const float mu = s * (1.0f / Dm);
  const float var = s2 * (1.0f / Dm) - mu * mu;
  const float inv = rsqrtf(var + 1e-6f);
  float* op = out + (size_t)row * Dm + lane * 8;
  const float* gp = g + lane * 8;
  const float* bp = be + lane * 8;
#pragma unroll
  for (int j = 0; j < 8; ++j) op[j] = (vv[j] - mu) * inv * gp[j] + bp[j];
}

// ------------------------------------------------------------------------------
extern "C" void kernel_launch(void* const* d_in, const int* in_sizes, int n_in,
                              void* d_out, int out_size, void* d_ws, size_t ws_size,
                              hipStream_t stream) {
  const float* q   = (const float*)d_in[0];
  const float* k   = (const float*)d_in[1];
  const float* v   = (const float*)d_in[2];
  const float* Wq  = (const float*)d_in[3];
  const float* Wk  = (const float*)d_in[4];
  const float* Wv  = (const float*)d_in[5];
  const float* Wfc = (const float*)d_in[6];
  const float* rel = (const float*)d_in[7];
  const float* gam = (const float*)d_in[8];
  const float* bet = (const float*)d_in[9];

  char* ws = (char*)d_ws;
  size_t off = 0;
  auto take = [&](size_t bytes) {
    char* p = ws + off;
    off += (bytes + 255) & ~(size_t)255;
    return p;
  };
  bf16_t* wqb  = (bf16_t*)take((size_t)Dm * Dm * 2);
  bf16_t* wkb  = (bf16_t*)take((size_t)Dm * Dm * 2);
  bf16_t* wvb  = (bf16_t*)take((size_t)Dm * Dm * 2);
  bf16_t* wfcb = (bf16_t*)take((size_t)Dm * Dm * 2);
  bf16_t* relb = (bf16_t*)take((size_t)NREL * DKd * 2);
  bf16_t* qb   = (bf16_t*)take((size_t)MTOK * Dm * 2);
  bf16_t* kb   = (bf16_t*)take((size_t)MTOK * Dm * 2);
  bf16_t* vb   = (bf16_t*)take((size_t)MTOK * Dm * 2);
  bf16_t* Qhp  = (bf16_t*)take((size_t)MTOK * Dm * 2);
  bf16_t* Khp  = (bf16_t*)take((size_t)MTOK * Dm * 2);
  bf16_t* Vtp  = (bf16_t*)take((size_t)MTOK * Dm * 2);
  bf16_t* posd = (bf16_t*)take((size_t)Bz * Hh * Lseq * NREL * 2);
  bf16_t* attnb= (bf16_t*)take((size_t)MTOK * Dm * 2);
  float*  yf   = (float*)take((size_t)MTOK * Dm * 4);

  auto cast = [&](const float* s, bf16_t* d, int n) {
    k_cast<<<dim3((n / 4 + 255) / 256), 256, 0, stream>>>(s, d, n);
  };
  cast(q, qb, MTOK * Dm);
  cast(k, kb, MTOK * Dm);
  cast(v, vb, MTOK * Dm);
  cast(Wq, wqb, Dm * Dm);
  cast(Wk, wkb, Dm * Dm);
  cast(Wv, wvb, Dm * Dm);
  cast(Wfc, wfcb, Dm * Dm);
  cast(rel, relb, NREL * DKd);

  dim3 gg(Dm / 64, MTOK / 64);
  k_gemm512<0><<<gg, 256, 0, stream>>>(qb, wqb, Qhp, nullptr, nullptr);
  k_gemm512<0><<<gg, 256, 0, stream>>>(kb, wkb, Khp, nullptr, nullptr);
  k_gemm512<1><<<gg, 256, 0, stream>>>(vb, wvb, Vtp, nullptr, nullptr);
  k_posdot<<<dim3(13, MTOK / 64), 256, 0, stream>>>(Qhp, relb, posd);
  k_attn<<<dim3(1024), 256, 0, stream>>>(Qhp, Khp, Vtp, posd, attnb);
  k_gemm512<2><<<gg, 256, 0, stream>>>(attnb, wfcb, nullptr, yf, q);
  k_ln<<<dim3(MTOK / 4), 256, 0, stream>>>(yf, gam, bet, (float*)d_out);
}